// Round 1
// baseline (1601.764 us; speedup 1.0000x reference)
//
#include <hip/hip_runtime.h>
#include <math.h>

// ---------------------------------------------------------------------------
// SwinV2-style block (DIM=192, HEADS=6, WS=8, SHIFT=4) on MI355X.
// Round 1: correctness-first. All heavy GEMMs via mfma_f32_16x16x32_bf16,
// bf16 inputs / f32 accum. Conv3x3 = implicit GEMM (9 shifted K-segments).
// ASSUMPTIONS (verify via bench): ws_size >= ~371 MB; mfma builtin takes
// short8 (ext_vector short) fragments per the gfx950 guide.
// ---------------------------------------------------------------------------

typedef unsigned short u16;
typedef __attribute__((ext_vector_type(8))) short short8;
typedef __attribute__((ext_vector_type(4))) float f32x4;

#define DI static __device__ __forceinline__

DI float b2f(u16 u){ union{unsigned u; float f;} v; v.u = ((unsigned)u)<<16; return v.f; }
DI u16 f2b(float f){ union{float f; unsigned u;} v; v.f = f; unsigned r = v.u + 0x7fffu + ((v.u>>16)&1u); return (u16)(r>>16); }
DI float gelu_f(float x){ return 0.5f*x*(1.0f+erff(x*0.7071067811865475f)); }

// ---------------- LayerNorm: f32 in -> bf16 out (row = 192 ch) -------------
__global__ __launch_bounds__(256) void ln_k(const float* __restrict__ in,
    const float* __restrict__ w, const float* __restrict__ b, u16* __restrict__ out)
{
  const int row  = blockIdx.x*4 + (threadIdx.x>>6);
  const int lane = threadIdx.x & 63;
  const float* r = in + (long)row*192;
  float v0 = r[lane], v1 = r[lane+64], v2 = r[lane+128];
  float s = v0+v1+v2;
  #pragma unroll
  for (int m=1;m<64;m<<=1) s += __shfl_xor(s, m);
  float mu = s*(1.0f/192.0f);
  float d0=v0-mu, d1=v1-mu, d2=v2-mu;
  float q = d0*d0+d1*d1+d2*d2;
  #pragma unroll
  for (int m=1;m<64;m<<=1) q += __shfl_xor(q, m);
  float rstd = rsqrtf(q*(1.0f/192.0f)+1e-5f);
  u16* o = out + (long)row*192;
  o[lane]     = f2b(d0*rstd*w[lane]    +b[lane]);
  o[lane+64]  = f2b(d1*rstd*w[lane+64] +b[lane+64]);
  o[lane+128] = f2b(d2*rstd*w[lane+128]+b[lane+128]);
}

// ------------- weight prep: f32->bf16 + conv re-layout + qkv bias ----------
__global__ __launch_bounds__(256) void prep_k(
    const float* __restrict__ qkv_w, const float* __restrict__ q_bias,
    const float* __restrict__ v_bias, const float* __restrict__ proj_w,
    const float* __restrict__ fc1_w, const float* __restrict__ fc2_w,
    const float* __restrict__ cab1_w, const float* __restrict__ cab2_w,
    const float* __restrict__ lgs,
    float* __restrict__ qkvbias, u16* __restrict__ wqkv, u16* __restrict__ wproj,
    u16* __restrict__ wfc1, u16* __restrict__ wfc2, u16* __restrict__ wt1,
    u16* __restrict__ wt2, float* __restrict__ scale6)
{
  int o = blockIdx.x*256 + threadIdx.x;
  if (o < 576){ qkvbias[o] = (o<192)? q_bias[o] : ((o<384)? 0.f : v_bias[o-384]); return; }
  o -= 576;
  if (o < 110592){ wqkv[o] = f2b(qkv_w[o]); return; } o -= 110592;
  if (o < 36864){ wproj[o] = f2b(proj_w[o]); return; } o -= 36864;
  if (o < 147456){ wfc1[o] = f2b(fc1_w[o]); return; } o -= 147456;
  if (o < 147456){ wfc2[o] = f2b(fc2_w[o]); return; } o -= 147456;
  if (o < 110592){ // wt1[s][oc(64)][ic(192)] <- cab1_w[oc][ic][kh][kw]
    int s = o/12288, r = o%12288, oc = r/192, ic = r%192, kh = s/3, kw = s%3;
    wt1[o] = f2b(cab1_w[((oc*192+ic)*3+kh)*3+kw]); return; } o -= 110592;
  if (o < 110592){ // wt2[s][oc(192)][ic(64)] <- cab2_w[oc][ic][kh][kw]
    int s = o/12288, r = o%12288, oc = r/64, ic = r%64, kh = s/3, kw = s%3;
    wt2[o] = f2b(cab2_w[((oc*64+ic)*3+kh)*3+kw]); return; } o -= 110592;
  if (o < 6){ scale6[o] = expf(fminf(lgs[o], logf(100.f))); }
}

// ------------- CPB MLP -> rpb16[h][n][m] = 16*sigmoid(bias) ----------------
__global__ __launch_bounds__(256) void rpb_k(const float* __restrict__ w1,
    const float* __restrict__ b1, const float* __restrict__ w2, float* __restrict__ rpb16)
{
  __shared__ float hb[225*6];
  const int tid = threadIdx.x;
  if (tid < 225){
    int di = tid/15, dj = tid%15;
    float vi = (di-7)*(8.0f/7.0f), vj = (dj-7)*(8.0f/7.0f);
    float t0 = (vi==0.f)?0.f:copysignf(log2f(fabsf(vi)+1.f)*(1.f/3.f), vi);
    float t1 = (vj==0.f)?0.f:copysignf(log2f(fabsf(vj)+1.f)*(1.f/3.f), vj);
    float acc[6] = {0,0,0,0,0,0};
    for (int hd=0; hd<512; ++hd){
      float a = fmaxf(t0*w1[hd*2] + t1*w1[hd*2+1] + b1[hd], 0.f);
      #pragma unroll
      for (int h=0;h<6;++h) acc[h] += a*w2[h*512+hd];
    }
    #pragma unroll
    for (int h=0;h<6;++h) hb[tid*6+h] = acc[h];
  }
  __syncthreads();
  for (int o = tid; o < 24576; o += 256){
    int h = o>>12, nm = o&4095, n = nm>>6, m = nm&63;
    int idx = ((n>>3)-(m>>3)+7)*15 + ((n&7)-(m&7)+7);
    rpb16[o] = 16.0f/(1.0f+expf(-hb[idx*6+h]));
  }
}

// ------------- generic bf16 MFMA GEMM: out = A(M,K) @ W(N,K)^T -------------
// SEGS>1 => conv mode: K-segments are 3x3 taps, A rows shifted+zero-masked.
// EPI: 0 qkv(+bias->bf16) 1 conv1(+bias,gelu->bf16) 2 conv2(+bias->f32)
//      3 proj(+bias + x + 0.01*c2*s -> f32) 4 fc1(+bias,gelu->bf16)
//      5 fc2(+bias accumulate into outf)
template<int EPI, int SEGS, int KSEG, int NN>
__global__ __launch_bounds__(256) void gemm_k(
    const u16* __restrict__ A, const u16* __restrict__ W,
    const float* __restrict__ bias, const float* __restrict__ resx,
    const float* __restrict__ c2, const float* __restrict__ sgate,
    float* __restrict__ outf, u16* __restrict__ outb)
{
  constexpr int STEPS = KSEG/32;
  constexpr int TOT = SEGS*STEPS;
  __shared__ __align__(16) u16 As[64*40];
  __shared__ __align__(16) u16 Bs[64*40];
  const int tid = threadIdx.x;
  const int wave = tid>>6, lane = tid&63;
  const int m0 = blockIdx.x*64, n0 = blockIdx.y*64;
  const int srow = tid>>2, scol = (tid&3)*8;
  const int fr = lane&15, fo = (lane>>4)*8;
  f32x4 acc[4] = {{0,0,0,0},{0,0,0,0},{0,0,0,0},{0,0,0,0}};
  for (int ks=0; ks<TOT; ++ks){
    const int seg = ks/STEPS;
    const int kin = (ks - seg*STEPS)*32;
    const int acol = kin + scol;
    short8 av = {0,0,0,0,0,0,0,0};
    {
      const int grow = m0 + srow;
      if constexpr (SEGS > 1){
        const int bb = grow>>14, yy = (grow>>7)&127, xx = grow&127;
        const int sy = yy + seg/3 - 1, sx = xx + seg%3 - 1;
        if ((unsigned)sy < 128u && (unsigned)sx < 128u)
          av = *(const short8*)(A + (long)((((bb<<7)|sy)<<7)|sx)*KSEG + acol);
      } else {
        av = *(const short8*)(A + (long)grow*KSEG + acol);
      }
    }
    short8 bv;
    if constexpr (SEGS > 1)
      bv = *(const short8*)(W + (long)seg*NN*KSEG + (long)(n0+srow)*KSEG + acol);
    else
      bv = *(const short8*)(W + (long)(n0+srow)*KSEG + acol);
    __syncthreads();                       // protect LDS reuse from prev iter
    *(short8*)(As + srow*40 + scol) = av;  // stride 40 bf16 = 80B: 16B-aligned
    *(short8*)(Bs + srow*40 + scol) = bv;
    __syncthreads();
    const short8 bfrag = *(const short8*)(Bs + (wave*16+fr)*40 + fo);
    #pragma unroll
    for (int m=0;m<4;++m){
      const short8 afrag = *(const short8*)(As + (m*16+fr)*40 + fo);
      acc[m] = __builtin_amdgcn_mfma_f32_16x16x32_bf16(afrag, bfrag, acc[m], 0, 0, 0);
    }
  }
  const int gcol = n0 + wave*16 + fr;      // C/D: col=lane&15
  const float bcol = bias[gcol];
  #pragma unroll
  for (int m=0;m<4;++m){
    #pragma unroll
    for (int i=0;i<4;++i){
      const int grow = m0 + m*16 + ((lane>>4)<<2) + i;  // row=(lane>>4)*4+reg
      const long o = (long)grow*NN + gcol;
      float v = acc[m][i];
      if constexpr (EPI==0){ outb[o] = f2b(v + bcol); }
      else if constexpr (EPI==1){ outb[o] = f2b(gelu_f(v + bcol)); }
      else if constexpr (EPI==2){ outf[o] = v + bcol; }
      else if constexpr (EPI==3){
        outf[o] = v + bcol + resx[o] + 0.01f*c2[o]*sgate[(grow>>14)*192 + gcol];
      }
      else if constexpr (EPI==4){ outb[o] = f2b(gelu_f(v + bcol)); }
      else { outf[o] = outf[o] + v + bcol; }
    }
  }
}

// ------------- squeeze: per-(b,c) spatial sum of c2 via atomics ------------
__global__ __launch_bounds__(192) void sqz_k(const float* __restrict__ c2,
                                             float* __restrict__ ssum)
{
  const int bid = blockIdx.x, b = bid>>6, chunk = bid&63, c = threadIdx.x;
  const float* p = c2 + ((long)b*16384 + chunk*256)*192 + c;
  float s = 0.f;
  for (int i=0;i<256;++i) s += p[(long)i*192];
  atomicAdd(&ssum[b*192+c], s);
}

// ------------- SE MLP: s = sigmoid(relu(mean@ca1^T+b1)@ca2^T+b2) -----------
__global__ __launch_bounds__(256) void se_k(const float* __restrict__ ssum,
    const float* __restrict__ ca1w, const float* __restrict__ ca1b,
    const float* __restrict__ ca2w, const float* __restrict__ ca2b,
    float* __restrict__ sgate)
{
  __shared__ float hid[48];
  const int tid = threadIdx.x;
  if (tid < 48){
    int b = tid/6, cs = tid%6;
    float a = ca1b[cs];
    for (int c=0;c<192;++c) a += ssum[b*192+c]*(1.f/16384.f)*ca1w[cs*192+c];
    hid[tid] = fmaxf(a, 0.f);
  }
  __syncthreads();
  for (int o = tid; o < 1536; o += 256){
    int b = o/192, c = o%192;
    float a = ca2b[c];
    #pragma unroll
    for (int cs=0;cs<6;++cs) a += hid[b*6+cs]*ca2w[c*6+cs];
    sgate[o] = 1.f/(1.f+expf(-a));
  }
}

// ------------- windowed cosine attention (1 block = 1 window) --------------
__global__ __launch_bounds__(256) void attn_k(const u16* __restrict__ qkv,
    const float* __restrict__ rpb16, const float* __restrict__ scale6,
    u16* __restrict__ aout)
{
  __shared__ float q_s[64*33], k_s[64*33], v_s[64*33];
  __shared__ float p_s[64*65];
  __shared__ float qinv[64], kinv[64];
  __shared__ int lidx[64], region[64];
  const int tid = threadIdx.x;
  const int bw = blockIdx.x;
  const int b = bw>>8, wn = bw&255, wy = wn>>4, wx = wn&15;
  if (tid < 64){
    int i = tid>>3, j = tid&7;
    int hs = wy*8+i, ws = wx*8+j;            // shifted-image coords
    lidx[tid] = (b<<14) | (((hs+4)&127)<<7) | ((ws+4)&127);
    int hb = hs<120?0:(hs<124?1:2), wb = ws<120?0:(ws<124?1:2);
    region[tid] = hb*3+wb;
  }
  __syncthreads();
  const int n = tid>>2, c0 = (tid&3)*8;
  for (int h=0; h<6; ++h){
    { // gather q,k,v for this head (bf16 -> f32 LDS, stride 33 vs conflicts)
      const long base = (long)lidx[n]*576 + h*32 + c0;
      short8 qv = *(const short8*)(qkv + base);
      short8 kv = *(const short8*)(qkv + base + 192);
      short8 vv = *(const short8*)(qkv + base + 384);
      #pragma unroll
      for (int e=0;e<8;++e){
        q_s[n*33+c0+e] = b2f((u16)qv[e]);
        k_s[n*33+c0+e] = b2f((u16)kv[e]);
        v_s[n*33+c0+e] = b2f((u16)vv[e]);
      }
    }
    __syncthreads();
    if (tid < 128){  // row L2 norms for cosine sim
      int r = tid & 63;
      const float* p = (tid<64)? q_s : k_s;
      float ss = 0.f;
      #pragma unroll
      for (int d=0;d<32;++d){ float t = p[r*33+d]; ss += t*t; }
      float inv = 1.0f / fmaxf(sqrtf(ss), 1e-12f);
      if (tid<64) qinv[r] = inv; else kinv[r] = inv;
    }
    __syncthreads();
    { // logits: cos*scale + 16*sigmoid(cpb) + mask
      const float scl = scale6[h];
      float qreg[32];
      #pragma unroll
      for (int d=0;d<32;++d) qreg[d] = q_s[n*33+d];
      const float qi = qinv[n];
      const int rn = region[n];
      const int mbase = (tid&3)*16;
      for (int mi=0; mi<16; ++mi){
        int m = mbase+mi;
        float dot = 0.f;
        #pragma unroll
        for (int d=0;d<32;++d) dot += qreg[d]*k_s[m*33+d];
        float lv = dot*qi*kinv[m]*scl + rpb16[h*4096 + n*64 + m];
        if (region[m] != rn) lv -= 100.0f;
        p_s[n*65+m] = lv;
      }
    }
    __syncthreads();
    if (tid < 64){   // softmax per row
      float mx = -1e30f;
      for (int m=0;m<64;++m) mx = fmaxf(mx, p_s[tid*65+m]);
      float sum = 0.f;
      for (int m=0;m<64;++m){ float e = expf(p_s[tid*65+m]-mx); p_s[tid*65+m]=e; sum+=e; }
      float inv = 1.0f/sum;
      for (int m=0;m<64;++m) p_s[tid*65+m] *= inv;
    }
    __syncthreads();
    { // PV + write bf16 out (concat-head, natural token order)
      float acc[8] = {0,0,0,0,0,0,0,0};
      for (int m=0;m<64;++m){
        float p = p_s[n*65+m];
        #pragma unroll
        for (int e=0;e<8;++e) acc[e] += p * v_s[m*33 + c0 + e];
      }
      short8 ov;
      #pragma unroll
      for (int e=0;e<8;++e) ov[e] = (short)f2b(acc[e]);
      *(short8*)(aout + (long)lidx[n]*192 + h*32 + c0) = ov;
    }
    __syncthreads();
  }
}

// ---------------------------------------------------------------------------
extern "C" void kernel_launch(void* const* d_in, const int* in_sizes, int n_in,
                              void* d_out, int out_size, void* d_ws, size_t ws_size,
                              hipStream_t stream)
{
  const float* x     = (const float*)d_in[0];
  const float* n1w   = (const float*)d_in[3];
  const float* n1b   = (const float*)d_in[4];
  const float* qkvw  = (const float*)d_in[5];
  const float* qb    = (const float*)d_in[6];
  const float* vb    = (const float*)d_in[7];
  const float* lgs   = (const float*)d_in[8];
  const float* cpb1w = (const float*)d_in[9];
  const float* cpb1b = (const float*)d_in[10];
  const float* cpb2w = (const float*)d_in[11];
  const float* projw = (const float*)d_in[12];
  const float* projb = (const float*)d_in[13];
  const float* cab1w = (const float*)d_in[14];
  const float* cab1b = (const float*)d_in[15];
  const float* cab2w = (const float*)d_in[16];
  const float* cab2b = (const float*)d_in[17];
  const float* ca1w  = (const float*)d_in[18];
  const float* ca1b  = (const float*)d_in[19];
  const float* ca2w  = (const float*)d_in[20];
  const float* ca2b  = (const float*)d_in[21];
  const float* n2w   = (const float*)d_in[22];
  const float* n2b   = (const float*)d_in[23];
  const float* fc1w  = (const float*)d_in[24];
  const float* fc1b  = (const float*)d_in[25];
  const float* fc2w  = (const float*)d_in[26];
  const float* fc2b  = (const float*)d_in[27];
  float* dout = (float*)d_out;
  char* ws = (char*)d_ws;

  // -------- workspace layout (liveness-aliased, ~371 MB total) --------
  constexpr size_t OFF_XN  = 0;                  // bf16 131072*192 (dead after qkv)
  constexpr size_t OFF_G1  = 50331648;           // bf16 131072*64  (dead after conv2)
  constexpr size_t OFF_C2  = 67108864;           // f32  131072*192 (dead after proj)
  constexpr size_t OFF_AO  = 167772160;          // bf16 131072*192 (dead after proj)
  constexpr size_t OFF_QKV = 218103808;          // bf16 131072*576 (dead after attn)
  constexpr size_t OFF_X2N = OFF_QKV;            // bf16 131072*192 (aliases qkv)
  constexpr size_t OFF_H1  = 0;                  // bf16 131072*768 (aliases xn..ao)
  constexpr size_t OFF_SM  = 369098752;          // small buffers (~1.5 MB)

  u16*   xn      = (u16*)(ws + OFF_XN);
  u16*   g1      = (u16*)(ws + OFF_G1);
  float* c2      = (float*)(ws + OFF_C2);
  u16*   ao      = (u16*)(ws + OFF_AO);
  u16*   qkvb    = (u16*)(ws + OFF_QKV);
  u16*   x2n     = (u16*)(ws + OFF_X2N);
  u16*   h1      = (u16*)(ws + OFF_H1);
  float* qkvbias = (float*)(ws + OFF_SM);
  float* scale6  = (float*)(ws + OFF_SM + 4096);
  float* ssum    = (float*)(ws + OFF_SM + 8192);
  float* sgate   = (float*)(ws + OFF_SM + 16384);
  float* rpb16   = (float*)(ws + OFF_SM + 24576);
  u16*   wqkv    = (u16*)(ws + OFF_SM + 131072);
  u16*   wproj   = (u16*)(ws + OFF_SM + 360448);
  u16*   wfc1    = (u16*)(ws + OFF_SM + 434176);
  u16*   wfc2    = (u16*)(ws + OFF_SM + 729088);
  u16*   wt1     = (u16*)(ws + OFF_SM + 1024000);
  u16*   wt2     = (u16*)(ws + OFF_SM + 1245184);

  // -------- launch sequence (stream-ordered) --------
  prep_k<<<2595, 256, 0, stream>>>(qkvw, qb, vb, projw, fc1w, fc2w, cab1w, cab2w,
                                   lgs, qkvbias, wqkv, wproj, wfc1, wfc2, wt1, wt2, scale6);
  rpb_k<<<1, 256, 0, stream>>>(cpb1w, cpb1b, cpb2w, rpb16);
  ln_k<<<32768, 256, 0, stream>>>(x, n1w, n1b, xn);
  // conv1: (131072,64) = conv3x3(xn) -> gelu -> g1 (implicit GEMM, 9 segs K=192)
  gemm_k<1,9,192,64><<<dim3(2048,1), 256, 0, stream>>>(xn, wt1, cab1b,
      nullptr, nullptr, nullptr, nullptr, g1);
  // conv2: (131072,192) = conv3x3(g1) -> c2 (f32)
  gemm_k<2,9,64,192><<<dim3(2048,3), 256, 0, stream>>>(g1, wt2, cab2b,
      nullptr, nullptr, nullptr, c2, nullptr);
  hipMemsetAsync(ssum, 0, 1536*4, stream);
  sqz_k<<<512, 192, 0, stream>>>(c2, ssum);
  se_k<<<1, 256, 0, stream>>>(ssum, ca1w, ca1b, ca2w, ca2b, sgate);
  // qkv (natural token order): (131072,576)
  gemm_k<0,1,192,576><<<dim3(2048,9), 256, 0, stream>>>(xn, wqkv, qkvbias,
      nullptr, nullptr, nullptr, nullptr, qkvb);
  attn_k<<<2048, 256, 0, stream>>>(qkvb, rpb16, scale6, ao);
  // proj + residual + CAB merge -> d_out = x + attn + 0.01*c2*s
  gemm_k<3,1,192,192><<<dim3(2048,3), 256, 0, stream>>>(ao, wproj, projb,
      x, c2, sgate, dout, nullptr);
  ln_k<<<32768, 256, 0, stream>>>(dout, n2w, n2b, x2n);
  // fc1 + gelu -> h1
  gemm_k<4,1,192,768><<<dim3(2048,12), 256, 0, stream>>>(x2n, wfc1, fc1b,
      nullptr, nullptr, nullptr, nullptr, h1);
  // fc2 accumulate into d_out
  gemm_k<5,1,768,192><<<dim3(2048,3), 256, 0, stream>>>(h1, wfc2, fc2b,
      nullptr, nullptr, nullptr, dout, nullptr);
}

// Round 2
// 832.018 us; speedup vs baseline: 1.9252x; 1.9252x over previous
//
#include <hip/hip_runtime.h>
#include <math.h>

// ---------------------------------------------------------------------------
// SwinV2-style block (DIM=192, HEADS=6, WS=8, SHIFT=4) on MI355X.
// Round 2: MFMA-based windowed attention (1 wave = 1 (window, head)).
// GEMM / LN / prep stages unchanged from round 1 (passed, absmax 0.031).
// ---------------------------------------------------------------------------

typedef unsigned short u16;
typedef __attribute__((ext_vector_type(8))) short short8;
typedef __attribute__((ext_vector_type(4))) float f32x4;

#define DI static __device__ __forceinline__

DI float b2f(u16 u){ union{unsigned u; float f;} v; v.u = ((unsigned)u)<<16; return v.f; }
DI u16 f2b(float f){ union{float f; unsigned u;} v; v.f = f; unsigned r = v.u + 0x7fffu + ((v.u>>16)&1u); return (u16)(r>>16); }
DI float gelu_f(float x){ return 0.5f*x*(1.0f+erff(x*0.7071067811865475f)); }

// ---------------- LayerNorm: f32 in -> bf16 out (row = 192 ch) -------------
__global__ __launch_bounds__(256) void ln_k(const float* __restrict__ in,
    const float* __restrict__ w, const float* __restrict__ b, u16* __restrict__ out)
{
  const int row  = blockIdx.x*4 + (threadIdx.x>>6);
  const int lane = threadIdx.x & 63;
  const float* r = in + (long)row*192;
  float v0 = r[lane], v1 = r[lane+64], v2 = r[lane+128];
  float s = v0+v1+v2;
  #pragma unroll
  for (int m=1;m<64;m<<=1) s += __shfl_xor(s, m);
  float mu = s*(1.0f/192.0f);
  float d0=v0-mu, d1=v1-mu, d2=v2-mu;
  float q = d0*d0+d1*d1+d2*d2;
  #pragma unroll
  for (int m=1;m<64;m<<=1) q += __shfl_xor(q, m);
  float rstd = rsqrtf(q*(1.0f/192.0f)+1e-5f);
  u16* o = out + (long)row*192;
  o[lane]     = f2b(d0*rstd*w[lane]    +b[lane]);
  o[lane+64]  = f2b(d1*rstd*w[lane+64] +b[lane+64]);
  o[lane+128] = f2b(d2*rstd*w[lane+128]+b[lane+128]);
}

// ------------- weight prep: f32->bf16 + conv re-layout + qkv bias ----------
__global__ __launch_bounds__(256) void prep_k(
    const float* __restrict__ qkv_w, const float* __restrict__ q_bias,
    const float* __restrict__ v_bias, const float* __restrict__ proj_w,
    const float* __restrict__ fc1_w, const float* __restrict__ fc2_w,
    const float* __restrict__ cab1_w, const float* __restrict__ cab2_w,
    const float* __restrict__ lgs,
    float* __restrict__ qkvbias, u16* __restrict__ wqkv, u16* __restrict__ wproj,
    u16* __restrict__ wfc1, u16* __restrict__ wfc2, u16* __restrict__ wt1,
    u16* __restrict__ wt2, float* __restrict__ scale6)
{
  int o = blockIdx.x*256 + threadIdx.x;
  if (o < 576){ qkvbias[o] = (o<192)? q_bias[o] : ((o<384)? 0.f : v_bias[o-384]); return; }
  o -= 576;
  if (o < 110592){ wqkv[o] = f2b(qkv_w[o]); return; } o -= 110592;
  if (o < 36864){ wproj[o] = f2b(proj_w[o]); return; } o -= 36864;
  if (o < 147456){ wfc1[o] = f2b(fc1_w[o]); return; } o -= 147456;
  if (o < 147456){ wfc2[o] = f2b(fc2_w[o]); return; } o -= 147456;
  if (o < 110592){ // wt1[s][oc(64)][ic(192)] <- cab1_w[oc][ic][kh][kw]
    int s = o/12288, r = o%12288, oc = r/192, ic = r%192, kh = s/3, kw = s%3;
    wt1[o] = f2b(cab1_w[((oc*192+ic)*3+kh)*3+kw]); return; } o -= 110592;
  if (o < 110592){ // wt2[s][oc(192)][ic(64)] <- cab2_w[oc][ic][kh][kw]
    int s = o/12288, r = o%12288, oc = r/64, ic = r%64, kh = s/3, kw = s%3;
    wt2[o] = f2b(cab2_w[((oc*64+ic)*3+kh)*3+kw]); return; } o -= 110592;
  if (o < 6){ scale6[o] = expf(fminf(lgs[o], logf(100.f))); }
}

// ---- CPB MLP -> rpbL in MFMA C-fragment order: [h][nQ][mK][lane][i] -------
// value = 16*sigmoid(bias[q][k][h]),  q = nQ*16+(lane&15), k = mK*16+(lane>>4)*4+i
__global__ __launch_bounds__(256) void rpb_k(const float* __restrict__ w1,
    const float* __restrict__ b1, const float* __restrict__ w2, float* __restrict__ rpbL)
{
  __shared__ float hb[225*6];
  const int tid = threadIdx.x;
  if (tid < 225){
    int di = tid/15, dj = tid%15;
    float vi = (di-7)*(8.0f/7.0f), vj = (dj-7)*(8.0f/7.0f);
    float t0 = (vi==0.f)?0.f:copysignf(log2f(fabsf(vi)+1.f)*(1.f/3.f), vi);
    float t1 = (vj==0.f)?0.f:copysignf(log2f(fabsf(vj)+1.f)*(1.f/3.f), vj);
    float acc[6] = {0,0,0,0,0,0};
    for (int hd=0; hd<512; ++hd){
      float a = fmaxf(t0*w1[hd*2] + t1*w1[hd*2+1] + b1[hd], 0.f);
      #pragma unroll
      for (int h=0;h<6;++h) acc[h] += a*w2[h*512+hd];
    }
    #pragma unroll
    for (int h=0;h<6;++h) hb[tid*6+h] = acc[h];
  }
  __syncthreads();
  for (int o = tid; o < 24576; o += 256){
    int i = o&3, lane = (o>>2)&63, mK = (o>>8)&3, nQ = (o>>10)&3, h = o>>12;
    int q = nQ*16 + (lane&15), k = mK*16 + (lane>>4)*4 + i;
    int idx = ((q>>3)-(k>>3)+7)*15 + ((q&7)-(k&7)+7);
    rpbL[o] = 16.0f/(1.0f+expf(-hb[idx*6+h]));
  }
}

// ------------- generic bf16 MFMA GEMM: out = A(M,K) @ W(N,K)^T -------------
template<int EPI, int SEGS, int KSEG, int NN>
__global__ __launch_bounds__(256) void gemm_k(
    const u16* __restrict__ A, const u16* __restrict__ W,
    const float* __restrict__ bias, const float* __restrict__ resx,
    const float* __restrict__ c2, const float* __restrict__ sgate,
    float* __restrict__ outf, u16* __restrict__ outb)
{
  constexpr int STEPS = KSEG/32;
  constexpr int TOT = SEGS*STEPS;
  __shared__ __align__(16) u16 As[64*40];
  __shared__ __align__(16) u16 Bs[64*40];
  const int tid = threadIdx.x;
  const int wave = tid>>6, lane = tid&63;
  const int m0 = blockIdx.x*64, n0 = blockIdx.y*64;
  const int srow = tid>>2, scol = (tid&3)*8;
  const int fr = lane&15, fo = (lane>>4)*8;
  f32x4 acc[4] = {{0,0,0,0},{0,0,0,0},{0,0,0,0},{0,0,0,0}};
  for (int ks=0; ks<TOT; ++ks){
    const int seg = ks/STEPS;
    const int kin = (ks - seg*STEPS)*32;
    const int acol = kin + scol;
    short8 av = {0,0,0,0,0,0,0,0};
    {
      const int grow = m0 + srow;
      if constexpr (SEGS > 1){
        const int bb = grow>>14, yy = (grow>>7)&127, xx = grow&127;
        const int sy = yy + seg/3 - 1, sx = xx + seg%3 - 1;
        if ((unsigned)sy < 128u && (unsigned)sx < 128u)
          av = *(const short8*)(A + (long)((((bb<<7)|sy)<<7)|sx)*KSEG + acol);
      } else {
        av = *(const short8*)(A + (long)grow*KSEG + acol);
      }
    }
    short8 bv;
    if constexpr (SEGS > 1)
      bv = *(const short8*)(W + (long)seg*NN*KSEG + (long)(n0+srow)*KSEG + acol);
    else
      bv = *(const short8*)(W + (long)(n0+srow)*KSEG + acol);
    __syncthreads();
    *(short8*)(As + srow*40 + scol) = av;
    *(short8*)(Bs + srow*40 + scol) = bv;
    __syncthreads();
    const short8 bfrag = *(const short8*)(Bs + (wave*16+fr)*40 + fo);
    #pragma unroll
    for (int m=0;m<4;++m){
      const short8 afrag = *(const short8*)(As + (m*16+fr)*40 + fo);
      acc[m] = __builtin_amdgcn_mfma_f32_16x16x32_bf16(afrag, bfrag, acc[m], 0, 0, 0);
    }
  }
  const int gcol = n0 + wave*16 + fr;
  const float bcol = bias[gcol];
  #pragma unroll
  for (int m=0;m<4;++m){
    #pragma unroll
    for (int i=0;i<4;++i){
      const int grow = m0 + m*16 + ((lane>>4)<<2) + i;
      const long o = (long)grow*NN + gcol;
      float v = acc[m][i];
      if constexpr (EPI==0){ outb[o] = f2b(v + bcol); }
      else if constexpr (EPI==1){ outb[o] = f2b(gelu_f(v + bcol)); }
      else if constexpr (EPI==2){ outf[o] = v + bcol; }
      else if constexpr (EPI==3){
        outf[o] = v + bcol + resx[o] + 0.01f*c2[o]*sgate[(grow>>14)*192 + gcol];
      }
      else if constexpr (EPI==4){ outb[o] = f2b(gelu_f(v + bcol)); }
      else { outf[o] = outf[o] + v + bcol; }
    }
  }
}

// ------------- squeeze: per-(b,c) spatial sum of c2 via atomics ------------
__global__ __launch_bounds__(192) void sqz_k(const float* __restrict__ c2,
                                             float* __restrict__ ssum)
{
  const int bid = blockIdx.x, b = bid>>6, chunk = bid&63, c = threadIdx.x;
  const float* p = c2 + ((long)b*16384 + chunk*256)*192 + c;
  float s = 0.f;
  for (int i=0;i<256;++i) s += p[(long)i*192];
  atomicAdd(&ssum[b*192+c], s);
}

// ------------- SE MLP ------------------------------------------------------
__global__ __launch_bounds__(256) void se_k(const float* __restrict__ ssum,
    const float* __restrict__ ca1w, const float* __restrict__ ca1b,
    const float* __restrict__ ca2w, const float* __restrict__ ca2b,
    float* __restrict__ sgate)
{
  __shared__ float hid[48];
  const int tid = threadIdx.x;
  if (tid < 48){
    int b = tid/6, cs = tid%6;
    float a = ca1b[cs];
    for (int c=0;c<192;++c) a += ssum[b*192+c]*(1.f/16384.f)*ca1w[cs*192+c];
    hid[tid] = fmaxf(a, 0.f);
  }
  __syncthreads();
  for (int o = tid; o < 1536; o += 256){
    int b = o/192, c = o%192;
    float a = ca2b[c];
    #pragma unroll
    for (int cs=0;cs<6;++cs) a += hid[b*6+cs]*ca2w[c*6+cs];
    sgate[o] = 1.f/(1.f+expf(-a));
  }
}

// ---------- MFMA windowed attention: 1 wave = 1 (window, head) -------------
// S^T = mfma(K, Q): lane holds S[q=lane&15(+16nQ)][k=mK*16+(lane>>4)*4+i]
// -> softmax = 16 in-lane values + shfl_xor(16,32). P -> LDS -> A-frags.
// PV = mfma(P, V^T-frag). All loads gathered via per-window lidx.
__global__ __launch_bounds__(256) void attn_k(const u16* __restrict__ qkv,
    const float* __restrict__ rpbL, const float* __restrict__ scale6,
    u16* __restrict__ aout)
{
  __shared__ int  lidx_s[4][64];
  __shared__ char region_s[4][64];
  __shared__ __align__(16) u16 p_s[4][64*72];   // 72-elem rows: 16B-aligned, 2-way banks
  const int tid = threadIdx.x, w = tid>>6, lane = tid&63;
  const int task = blockIdx.x*4 + w;            // 12288 = 2048 windows * 6 heads
  const int win = task/6, h = task - win*6;
  const int b = win>>8, wn = win&255, wy = wn>>4, wx = wn&15;
  {
    int i = lane>>3, j = lane&7;
    int hs = wy*8+i, ws = wx*8+j;
    lidx_s[w][lane] = (b<<14) | (((hs+4)&127)<<7) | ((ws+4)&127);
    int hb = hs<120?0:(hs<124?1:2), wb = ws<120?0:(ws<124?1:2);
    region_s[w][lane] = (char)(hb*3+wb);
  }
  __syncthreads();
  const int g = lane>>4, l15 = lane&15;
  const bool edge = (wy==15) || (wx==15);
  const float scl = scale6[h];
  const f32x4 zf = {0.f,0.f,0.f,0.f};

  // ---- K fragments (normalized bf16) ----
  short8 kf[4];
  #pragma unroll
  for (int mt=0; mt<4; ++mt){
    const long base = (long)lidx_s[w][mt*16+l15]*576 + 192 + h*32 + g*8;
    short8 r = *(const short8*)(qkv + base);
    float f[8]; float ss = 0.f;
    #pragma unroll
    for (int e=0;e<8;++e){ f[e] = b2f((u16)r[e]); ss += f[e]*f[e]; }
    ss += __shfl_xor(ss,16); ss += __shfl_xor(ss,32);
    const float inv = 1.0f/fmaxf(sqrtf(ss), 1e-12f);
    #pragma unroll
    for (int e=0;e<8;++e) kf[mt][e] = (short)f2b(f[e]*inv);
  }

  // ---- per-Q-tile: QK^T, logits, softmax, pack P to LDS ----
  #pragma unroll
  for (int nt=0; nt<4; ++nt){
    short8 qf;
    {
      const long base = (long)lidx_s[w][nt*16+l15]*576 + h*32 + g*8;
      short8 r = *(const short8*)(qkv + base);
      float f[8]; float ss = 0.f;
      #pragma unroll
      for (int e=0;e<8;++e){ f[e] = b2f((u16)r[e]); ss += f[e]*f[e]; }
      ss += __shfl_xor(ss,16); ss += __shfl_xor(ss,32);
      const float inv = 1.0f/fmaxf(sqrtf(ss), 1e-12f);
      #pragma unroll
      for (int e=0;e<8;++e) qf[e] = (short)f2b(f[e]*inv);
    }
    f32x4 st[4];
    #pragma unroll
    for (int mt=0; mt<4; ++mt)
      st[mt] = __builtin_amdgcn_mfma_f32_16x16x32_bf16(kf[mt], qf, zf, 0, 0, 0);
    // logits
    float lv[16];
    const float* rp = rpbL + ((h*4+nt)*4)*256 + lane*4;
    const int rq = edge ? region_s[w][nt*16+l15] : 0;
    #pragma unroll
    for (int mt=0; mt<4; ++mt){
      const f32x4 rb = *(const f32x4*)(rp + mt*256);
      #pragma unroll
      for (int i=0;i<4;++i){
        float v = st[mt][i]*scl + rb[i];
        if (edge && region_s[w][mt*16+g*4+i] != rq) v -= 100.0f;
        lv[mt*4+i] = v;
      }
    }
    // softmax over 64 k (16 in-lane + 4 lane-groups)
    float mx = lv[0];
    #pragma unroll
    for (int t=1;t<16;++t) mx = fmaxf(mx, lv[t]);
    mx = fmaxf(mx, __shfl_xor(mx,16)); mx = fmaxf(mx, __shfl_xor(mx,32));
    float sum = 0.f;
    #pragma unroll
    for (int t=0;t<16;++t){ lv[t] = __expf(lv[t]-mx); sum += lv[t]; }
    sum += __shfl_xor(sum,16); sum += __shfl_xor(sum,32);
    const float isum = 1.0f/sum;
    u16* pr = p_s[w] + (nt*16+l15)*72;
    #pragma unroll
    for (int mt=0; mt<4; ++mt){
      #pragma unroll
      for (int j=0;j<2;++j){
        unsigned lo = f2b(lv[mt*4+2*j]  *isum);
        unsigned hi = f2b(lv[mt*4+2*j+1]*isum);
        *(unsigned*)(pr + mt*16 + g*4 + 2*j) = lo | (hi<<16);
      }
    }
  }

  // ---- V^T B-fragments (gathered) ----
  short8 vf[2][2];
  #pragma unroll
  for (int nd=0; nd<2; ++nd)
    #pragma unroll
    for (int kc=0; kc<2; ++kc)
      #pragma unroll
      for (int e=0;e<8;++e){
        const int tok = kc*32 + g*8 + e;
        vf[nd][kc][e] = (short)qkv[(long)lidx_s[w][tok]*576 + 384 + h*32 + nd*16 + l15];
      }

  __syncthreads();   // P_lds writes (all lanes) visible before A-frag reads

  // ---- PV + epilogue ----
  #pragma unroll
  for (int mt=0; mt<4; ++mt){
    const short8 a0 = *(const short8*)(p_s[w] + (mt*16+l15)*72 +      g*8);
    const short8 a1 = *(const short8*)(p_s[w] + (mt*16+l15)*72 + 32 + g*8);
    #pragma unroll
    for (int nd=0; nd<2; ++nd){
      f32x4 o = __builtin_amdgcn_mfma_f32_16x16x32_bf16(a0, vf[nd][0], zf, 0, 0, 0);
      o = __builtin_amdgcn_mfma_f32_16x16x32_bf16(a1, vf[nd][1], o, 0, 0, 0);
      #pragma unroll
      for (int i=0;i<4;++i){
        const int q = mt*16 + g*4 + i;
        aout[(long)lidx_s[w][q]*192 + h*32 + nd*16 + l15] = f2b(o[i]);
      }
    }
  }
}

// ---------------------------------------------------------------------------
extern "C" void kernel_launch(void* const* d_in, const int* in_sizes, int n_in,
                              void* d_out, int out_size, void* d_ws, size_t ws_size,
                              hipStream_t stream)
{
  const float* x     = (const float*)d_in[0];
  const float* n1w   = (const float*)d_in[3];
  const float* n1b   = (const float*)d_in[4];
  const float* qkvw  = (const float*)d_in[5];
  const float* qb    = (const float*)d_in[6];
  const float* vb    = (const float*)d_in[7];
  const float* lgs   = (const float*)d_in[8];
  const float* cpb1w = (const float*)d_in[9];
  const float* cpb1b = (const float*)d_in[10];
  const float* cpb2w = (const float*)d_in[11];
  const float* projw = (const float*)d_in[12];
  const float* projb = (const float*)d_in[13];
  const float* cab1w = (const float*)d_in[14];
  const float* cab1b = (const float*)d_in[15];
  const float* cab2w = (const float*)d_in[16];
  const float* cab2b = (const float*)d_in[17];
  const float* ca1w  = (const float*)d_in[18];
  const float* ca1b  = (const float*)d_in[19];
  const float* ca2w  = (const float*)d_in[20];
  const float* ca2b  = (const float*)d_in[21];
  const float* n2w   = (const float*)d_in[22];
  const float* n2b   = (const float*)d_in[23];
  const float* fc1w  = (const float*)d_in[24];
  const float* fc1b  = (const float*)d_in[25];
  const float* fc2w  = (const float*)d_in[26];
  const float* fc2b  = (const float*)d_in[27];
  float* dout = (float*)d_out;
  char* ws = (char*)d_ws;

  constexpr size_t OFF_XN  = 0;
  constexpr size_t OFF_G1  = 50331648;
  constexpr size_t OFF_C2  = 67108864;
  constexpr size_t OFF_AO  = 167772160;
  constexpr size_t OFF_QKV = 218103808;
  constexpr size_t OFF_X2N = OFF_QKV;
  constexpr size_t OFF_H1  = 0;
  constexpr size_t OFF_SM  = 369098752;

  u16*   xn      = (u16*)(ws + OFF_XN);
  u16*   g1      = (u16*)(ws + OFF_G1);
  float* c2      = (float*)(ws + OFF_C2);
  u16*   ao      = (u16*)(ws + OFF_AO);
  u16*   qkvb    = (u16*)(ws + OFF_QKV);
  u16*   x2n     = (u16*)(ws + OFF_X2N);
  u16*   h1      = (u16*)(ws + OFF_H1);
  float* qkvbias = (float*)(ws + OFF_SM);
  float* scale6  = (float*)(ws + OFF_SM + 4096);
  float* ssum    = (float*)(ws + OFF_SM + 8192);
  float* sgate   = (float*)(ws + OFF_SM + 16384);
  float* rpbL    = (float*)(ws + OFF_SM + 24576);
  u16*   wqkv    = (u16*)(ws + OFF_SM + 131072);
  u16*   wproj   = (u16*)(ws + OFF_SM + 360448);
  u16*   wfc1    = (u16*)(ws + OFF_SM + 434176);
  u16*   wfc2    = (u16*)(ws + OFF_SM + 729088);
  u16*   wt1     = (u16*)(ws + OFF_SM + 1024000);
  u16*   wt2     = (u16*)(ws + OFF_SM + 1245184);

  prep_k<<<2595, 256, 0, stream>>>(qkvw, qb, vb, projw, fc1w, fc2w, cab1w, cab2w,
                                   lgs, qkvbias, wqkv, wproj, wfc1, wfc2, wt1, wt2, scale6);
  rpb_k<<<1, 256, 0, stream>>>(cpb1w, cpb1b, cpb2w, rpbL);
  ln_k<<<32768, 256, 0, stream>>>(x, n1w, n1b, xn);
  gemm_k<1,9,192,64><<<dim3(2048,1), 256, 0, stream>>>(xn, wt1, cab1b,
      nullptr, nullptr, nullptr, nullptr, g1);
  gemm_k<2,9,64,192><<<dim3(2048,3), 256, 0, stream>>>(g1, wt2, cab2b,
      nullptr, nullptr, nullptr, c2, nullptr);
  hipMemsetAsync(ssum, 0, 1536*4, stream);
  sqz_k<<<512, 192, 0, stream>>>(c2, ssum);
  se_k<<<1, 256, 0, stream>>>(ssum, ca1w, ca1b, ca2w, ca2b, sgate);
  gemm_k<0,1,192,576><<<dim3(2048,9), 256, 0, stream>>>(xn, wqkv, qkvbias,
      nullptr, nullptr, nullptr, nullptr, qkvb);
  attn_k<<<3072, 256, 0, stream>>>(qkvb, rpbL, scale6, ao);
  gemm_k<3,1,192,192><<<dim3(2048,3), 256, 0, stream>>>(ao, wproj, projb,
      x, c2, sgate, dout, nullptr);
  ln_k<<<32768, 256, 0, stream>>>(dout, n2w, n2b, x2n);
  gemm_k<4,1,192,768><<<dim3(2048,12), 256, 0, stream>>>(x2n, wfc1, fc1b,
      nullptr, nullptr, nullptr, nullptr, h1);
  gemm_k<5,1,768,192><<<dim3(2048,3), 256, 0, stream>>>(h1, wfc2, fc2b,
      nullptr, nullptr, nullptr, dout, nullptr);
}